// Round 7
// baseline (192.009 us; speedup 1.0000x reference)
//
#include <hip/hip_runtime.h>
#include <hip/hip_bf16.h>

// ---- problem constants ----
#define T_DIM   2048
#define A_DIM   64
#define N_TOK   (T_DIM * A_DIM)     // 131072
#define RAWOB   120
#define N_TP    5
#define E_EXP   10
#define D_DIM   126                  // RAWOB + N_TP + 1
#define DP      128                  // padded K
#define H_DIM   128
#define N_ACT   16
#define CAP     14336                // per-expert capacity (mean 13107, +11 sigma)
#define MTILE   64                   // tokens per block (4 waves x 16)
#define MAXC    (CAP / MTILE)        // 224 chunks per expert
#define LOGITS_SZ (N_TOK * N_ACT)    // 2097152
#define HB_STRIDE 136                // padded h-tile row stride (ushorts)

typedef __bf16 bh8 __attribute__((ext_vector_type(8)));
typedef ushort u16x8 __attribute__((ext_vector_type(8)));
typedef float  f32x4 __attribute__((ext_vector_type(4)));

__device__ __forceinline__ f32x4 mfma16(bh8 a, bh8 b, f32x4 c) {
    return __builtin_amdgcn_mfma_f32_16x16x32_bf16(a, b, c, 0, 0, 0);
}

__device__ __forceinline__ ushort f2bf(float f) {
    unsigned x = __builtin_bit_cast(unsigned, f);
    unsigned r = (x + 0x7fffu + ((x >> 16) & 1u)) >> 16;   // round-nearest-even
    return (ushort)r;
}

// ---------------- kernel 0: weight transpose f32 -> bf16 + counter zero ----------------
// W1t[e][h][d] (d-contig, d padded to 128 w/ zeros), W2t[e][a][h], Wc1t[h][d]
#define W1T_N (E_EXP * H_DIM * DP)           // 163840
#define W2T_N (E_EXP * N_ACT * H_DIM)        // 20480
#define WC1T_N (DP * DP)                     // 16384
#define PREP_BLOCKS 124

__global__ __launch_bounds__(256) void prep_kernel(
    const float* __restrict__ W1, const float* __restrict__ W2,
    const float* __restrict__ Wc1,
    int* __restrict__ counts, ushort* __restrict__ W1t,
    ushort* __restrict__ W2t, ushort* __restrict__ Wc1t)
{
    int bx = blockIdx.x, tid = threadIdx.x;
    if (bx < 44) {
        __shared__ ushort st[32][130];   // 32 d-rows x 128 h, padded
        const float* src;
        ushort* dstbase;
        int d0;
        if (bx < 40) {
            int e = bx >> 2;
            d0 = (bx & 3) * 32;
            src = W1 + (e * D_DIM + d0) * H_DIM;
            dstbase = W1t + e * H_DIM * DP;
        } else {
            d0 = (bx - 40) * 32;
            src = Wc1 + d0 * H_DIM;
            dstbase = Wc1t;
        }
        int dmax = D_DIM - d0;           // 32,32,32,30
#pragma unroll
        for (int p = 0; p < 16; ++p) {
            int idx = p * 256 + tid;
            int dd = idx >> 7, h = idx & 127;
            float v = (dd < dmax) ? src[dd * H_DIM + h] : 0.f;  // coalesced in h
            st[dd][h] = f2bf(v);
        }
        __syncthreads();
#pragma unroll
        for (int p = 0; p < 16; ++p) {
            int idx = p * 256 + tid;
            int h = idx >> 5, d = idx & 31;
            dstbase[h * DP + d0 + d] = st[d][h];                // 64B runs in d
        }
    } else {
        int i = (bx - 44) * 256 + tid;   // [0, 20480)
        int h = i & 127;
        int a = (i >> 7) & 15;
        int e = i >> 11;
        W2t[(e * N_ACT + a) * H_DIM + h] = f2bf(W2[(e * H_DIM + h) * N_ACT + a]);
        if (bx == 44 && tid < 160) counts[tid] = 0;
    }
}

// ---------------- kernel 1: bucket tokens by expert ----------------
// counts padded: expert e lives at counts[e*16] (own 64B line)
#define BUCKET_BLOCKS 128
__global__ __launch_bounds__(256) void bucket_kernel(
    const int* __restrict__ pick, int* __restrict__ counts, int* __restrict__ order)
{
    __shared__ int lc[E_EXP], lb[E_EXP], lcur[E_EXP];
    int tid = threadIdx.x;
    if (tid < E_EXP) { lc[tid] = 0; lcur[tid] = 0; }
    __syncthreads();
    int base = blockIdx.x * 1024;
    int e4[4];
#pragma unroll
    for (int it = 0; it < 4; ++it) {
        e4[it] = pick[base + it * 256 + tid];
        atomicAdd(&lc[e4[it]], 1);
    }
    __syncthreads();
    if (tid < E_EXP) lb[tid] = atomicAdd(&counts[tid * 16], lc[tid]);
    __syncthreads();
#pragma unroll
    for (int it = 0; it < 4; ++it) {
        int e = e4[it];
        int pos = lb[e] + atomicAdd(&lcur[e], 1);
        if (pos < CAP) order[e * CAP + pos] = base + it * 256 + tid;
    }
}

// ---------------- kernel 2: wave-autonomous fused expert + critic ----------------
// Each wave owns 16 tokens. A-fragments loaded straight from obs (no x staging,
// no barriers). Only LDS: per-wave h-tile for the L1->L2 lane transpose.
__global__ __launch_bounds__(256, 6) void moe_kernel(
    const float* __restrict__ obs, const int* __restrict__ hete_type,
    const int* __restrict__ gp_sel,
    const float* __restrict__ b1, const float* __restrict__ b2,
    const float* __restrict__ bc1, const float* __restrict__ bc2,
    const int* __restrict__ counts, const int* __restrict__ order,
    const ushort* __restrict__ W1t, const ushort* __restrict__ W2t,
    const ushort* __restrict__ Wc1t, const float* __restrict__ Wc2,
    float* __restrict__ out)
{
    __shared__ __align__(16) ushort hbuf[4][16 * HB_STRIDE];   // per-wave h tile

    const int bx = blockIdx.x;
    const int e = bx % E_EXP;
    const int c = bx / E_EXP;
    const int cnt = counts[e * 16];
    const int tid = threadIdx.x;
    const int w = tid >> 6;
    const int base = c * MTILE + w * 16;      // this wave's token offset in bucket
    if (base >= cnt) return;                   // per-wave exit (no barriers below)

    const int l = tid & 63;
    const int lm = l & 15;                     // A-row / token slot
    const int lq = l >> 4;                     // k-quad

    const int slot = min(base + lm, cnt - 1);
    const int tok = order[e * CAP + slot];

    // ---- build A-fragments directly from obs (+augment), f32 -> bf16 ----
    bh8 a[4];
    {
        const float* orow = obs + tok * RAWOB;
#pragma unroll
        for (int kt = 0; kt < 3; ++kt) {
            const float* p = orow + kt * 32 + lq * 8;
            float4 u0 = *(const float4*)(const void*)p;
            float4 u1 = *(const float4*)(const void*)(p + 4);
            u16x8 t;
            t[0] = f2bf(u0.x); t[1] = f2bf(u0.y); t[2] = f2bf(u0.z); t[3] = f2bf(u0.w);
            t[4] = f2bf(u1.x); t[5] = f2bf(u1.y); t[6] = f2bf(u1.z); t[7] = f2bf(u1.w);
            a[kt] = __builtin_bit_cast(bh8, t);
        }
        u16x8 t;
        if (lq < 3) {   // k = 96..119 from obs
            const float* p = orow + 96 + lq * 8;
            float4 u0 = *(const float4*)(const void*)p;
            float4 u1 = *(const float4*)(const void*)(p + 4);
            t[0] = f2bf(u0.x); t[1] = f2bf(u0.y); t[2] = f2bf(u0.z); t[3] = f2bf(u0.w);
            t[4] = f2bf(u1.x); t[5] = f2bf(u1.y); t[6] = f2bf(u1.z); t[7] = f2bf(u1.w);
        } else {        // k = 120..127: [hete_type, gp_obs(5), 0, 0]
            int ht = hete_type[tok];
            int tt = tok >> 6;                 // token / A_DIM
            t[0] = f2bf((float)ht);
#pragma unroll
            for (int q = 0; q < N_TP; ++q) {
                float g = (q == ht) ? -1.0f : (float)gp_sel[tt * N_TP + q];
                t[1 + q] = f2bf(g);
            }
            t[6] = 0; t[7] = 0;
        }
        a[3] = __builtin_bit_cast(bh8, t);
    }

    // ---- fused expert-L1 + critic-L1 over 8 n-tiles of 16 ----
    ushort* hrow = &hbuf[w][0];
    const ushort* W1e = W1t + e * DP * DP;
    float part[4] = {0.f, 0.f, 0.f, 0.f};
#pragma unroll
    for (int nt = 0; nt < 8; ++nt) {
        const int n = nt * 16 + lm;
        f32x4 ae = (f32x4){0.f, 0.f, 0.f, 0.f};
        f32x4 ac = (f32x4){0.f, 0.f, 0.f, 0.f};
#pragma unroll
        for (int kt = 0; kt < 4; ++kt) {
            bh8 be = *(const bh8*)(const void*)(W1e + n * DP + kt * 32 + lq * 8);
            bh8 bc = *(const bh8*)(const void*)(Wc1t + n * DP + kt * 32 + lq * 8);
            ae = mfma16(a[kt], be, ae);
            ac = mfma16(a[kt], bc, ac);
        }
        float bn = b1[e * H_DIM + n];
        float cn = bc1[n];
        float wc = Wc2[n];
#pragma unroll
        for (int r = 0; r < 4; ++r) {
            // C layout: col n = lane&15, row m = lq*4 + r
            float hv = fmaxf(ae[r] + bn, 0.f);
            hrow[(lq * 4 + r) * HB_STRIDE + n] = f2bf(hv);
            part[r] += fmaxf(ac[r] + cn, 0.f) * wc;
        }
    }

    // ---- critic: reduce partials over the 16 lm lanes, write values ----
#pragma unroll
    for (int mask = 1; mask < 16; mask <<= 1)
#pragma unroll
        for (int r = 0; r < 4; ++r)
            part[r] += __shfl_xor(part[r], mask, 64);
    if (lm == 0) {
        float bcv = bc2[0];
#pragma unroll
        for (int r = 0; r < 4; ++r) {
            int m = lq * 4 + r;
            if (base + m < cnt) {
                int tm = order[e * CAP + base + m];
                out[LOGITS_SZ + tm] = part[r] + bcv;
            }
        }
    }

    // ---- expert layer 2: y = h @ W2[e] + b2[e]  (A-frags from hbuf) ----
    {
        f32x4 y = (f32x4){0.f, 0.f, 0.f, 0.f};
#pragma unroll
        for (int kt = 0; kt < 4; ++kt) {
            bh8 hf = *(const bh8*)(const void*)(hrow + lm * HB_STRIDE + kt * 32 + lq * 8);
            bh8 bf = *(const bh8*)(const void*)
                (W2t + (e * N_ACT + lm) * H_DIM + kt * 32 + lq * 8);
            y = mfma16(hf, bf, y);
        }
        float bb = b2[e * N_ACT + lm];
#pragma unroll
        for (int r = 0; r < 4; ++r) {
            int m = lq * 4 + r;
            if (base + m < cnt) {
                int tm = order[e * CAP + base + m];
                out[tm * N_ACT + lm] = y[r] + bb;
            }
        }
    }
}

extern "C" void kernel_launch(void* const* d_in, const int* in_sizes, int n_in,
                              void* d_out, int out_size, void* d_ws, size_t ws_size,
                              hipStream_t stream) {
    const float* obs  = (const float*)d_in[0];
    const int*   pick = (const int*)d_in[1];
    const int*   htyp = (const int*)d_in[2];
    const int*   gp   = (const int*)d_in[3];
    const float* W1   = (const float*)d_in[4];
    const float* b1   = (const float*)d_in[5];
    const float* W2   = (const float*)d_in[6];
    const float* b2   = (const float*)d_in[7];
    const float* Wc1  = (const float*)d_in[8];
    const float* bc1  = (const float*)d_in[9];
    const float* Wc2  = (const float*)d_in[10];
    const float* bc2  = (const float*)d_in[11];
    float* out = (float*)d_out;

    int*    counts = (int*)d_ws;              // 160 ints (padded, e -> counts[e*16])
    int*    order  = counts + 160;            // E_EXP * CAP ints
    ushort* W1t    = (ushort*)(order + E_EXP * CAP);
    ushort* W2t    = W1t + W1T_N;
    ushort* Wc1t   = W2t + W2T_N;

    prep_kernel<<<PREP_BLOCKS, 256, 0, stream>>>(
        W1, W2, Wc1, counts, W1t, W2t, Wc1t);
    bucket_kernel<<<BUCKET_BLOCKS, 256, 0, stream>>>(pick, counts, order);
    moe_kernel<<<E_EXP * MAXC, 256, 0, stream>>>(
        obs, htyp, gp, b1, b2, bc1, bc2, counts, order,
        W1t, W2t, Wc1t, Wc2, out);
}

// Round 8
// 150.674 us; speedup vs baseline: 1.2743x; 1.2743x over previous
//
#include <hip/hip_runtime.h>
#include <hip/hip_bf16.h>

// ---- problem constants ----
#define T_DIM   2048
#define A_DIM   64
#define N_TOK   (T_DIM * A_DIM)     // 131072
#define RAWOB   120
#define N_TP    5
#define E_EXP   10
#define D_DIM   126                  // RAWOB + N_TP + 1
#define DP      128                  // padded K
#define H_DIM   128
#define N_ACT   16
#define CAP     14336                // per-expert capacity (mean 13107, +11 sigma)
#define BTOK    128                  // tokens per block (4 waves x 32)
#define MAXC    (CAP / BTOK)         // 112 chunks per expert
#define LOGITS_SZ (N_TOK * N_ACT)    // 2097152
#define HB_STRIDE 136                // padded h-tile row stride (ushorts, 16B-aligned)

typedef __bf16 bh8 __attribute__((ext_vector_type(8)));
typedef ushort u16x8 __attribute__((ext_vector_type(8)));
typedef float  f32x4 __attribute__((ext_vector_type(4)));

__device__ __forceinline__ f32x4 mfma16(bh8 a, bh8 b, f32x4 c) {
    return __builtin_amdgcn_mfma_f32_16x16x32_bf16(a, b, c, 0, 0, 0);
}

__device__ __forceinline__ ushort f2bf(float f) {
    unsigned x = __builtin_bit_cast(unsigned, f);
    unsigned r = (x + 0x7fffu + ((x >> 16) & 1u)) >> 16;   // round-nearest-even
    return (ushort)r;
}

// ---------------- kernel 0: fragment-major weight packing (f32 -> bf16) ----------
// W1p[e][nt][kt][lane][8]: the 1KB B-fragment a wave consumes per (nt,kt) is
// contiguous; lane l (lm=l&15, lq=l>>4) holds W1[d=kt*32+lq*8 .. +8][n=nt*16+lm].
// Same for Wc1p (no e) and W2p[e][kt][lane][8] (n -> action).
#define W1P_N (E_EXP * H_DIM * DP)           // 163840 ushorts
#define W2P_N (E_EXP * N_ACT * H_DIM)        // 20480
#define WC1P_N (DP * DP)                     // 16384
#define PREP_BLOCKS 124

__global__ __launch_bounds__(256) void prep_kernel(
    const float* __restrict__ W1, const float* __restrict__ W2,
    const float* __restrict__ Wc1,
    int* __restrict__ counts, ushort* __restrict__ W1p,
    ushort* __restrict__ W2p, ushort* __restrict__ Wc1p)
{
    int bx = blockIdx.x, tid = threadIdx.x;
    if (bx < 44) {
        __shared__ ushort st[32][130];   // 32 d-rows x 128 n, padded
        const float* src;
        ushort* dstbase;
        int kt;
        if (bx < 40) {                   // W1: e = bx>>2, kt = bx&3
            int e = bx >> 2;
            kt = bx & 3;
            src = W1 + (e * D_DIM + kt * 32) * H_DIM;
            dstbase = W1p + e * (H_DIM * DP);
        } else {                         // Wc1: kt = bx-40
            kt = bx - 40;
            src = Wc1 + kt * 32 * H_DIM;
            dstbase = Wc1p;
        }
        int dmax = D_DIM - kt * 32;      // 32,32,32,30
#pragma unroll
        for (int p = 0; p < 16; ++p) {
            int idx = p * 256 + tid;
            int dd = idx >> 7, n = idx & 127;
            float v = (dd < dmax) ? src[dd * H_DIM + n] : 0.f;  // coalesced in n
            st[dd][n] = f2bf(v);
        }
        __syncthreads();
#pragma unroll
        for (int p = 0; p < 16; ++p) {
            int idx = p * 256 + tid;
            int dd = idx >> 7, n = idx & 127;
            // frag position: nt=n>>4, lm=n&15, lq=dd>>3, j=dd&7
            dstbase[((n >> 4) * 4 + kt) * 512 + ((dd >> 3) * 16 + (n & 15)) * 8 + (dd & 7)]
                = st[dd][n];
        }
    } else {
        int i = (bx - 44) * 256 + tid;   // [0, 20480)
        int j = i & 7;
        int l = (i >> 3) & 63;
        int kt = (i >> 9) & 3;
        int e = i >> 11;
        int lm = l & 15, lq = l >> 4;
        W2p[i] = f2bf(W2[(e * H_DIM + kt * 32 + lq * 8 + j) * N_ACT + lm]);
        if (bx == 44 && tid < 160) counts[tid] = 0;
    }
}

// ---------------- kernel 1: bucket tokens by expert ----------------
// counts padded: expert e lives at counts[e*16] (own 64B line)
#define BUCKET_BLOCKS 128
__global__ __launch_bounds__(256) void bucket_kernel(
    const int* __restrict__ pick, int* __restrict__ counts, int* __restrict__ order)
{
    __shared__ int lc[E_EXP], lb[E_EXP], lcur[E_EXP];
    int tid = threadIdx.x;
    if (tid < E_EXP) { lc[tid] = 0; lcur[tid] = 0; }
    __syncthreads();
    int base = blockIdx.x * 1024;
    int e4[4];
#pragma unroll
    for (int it = 0; it < 4; ++it) {
        e4[it] = pick[base + it * 256 + tid];
        atomicAdd(&lc[e4[it]], 1);
    }
    __syncthreads();
    if (tid < E_EXP) lb[tid] = atomicAdd(&counts[tid * 16], lc[tid]);
    __syncthreads();
#pragma unroll
    for (int it = 0; it < 4; ++it) {
        int e = e4[it];
        int pos = lb[e] + atomicAdd(&lcur[e], 1);
        if (pos < CAP) order[e * CAP + pos] = base + it * 256 + tid;
    }
}

// ---------------- kernel 2: wave-autonomous fused expert + critic ----------------
// Each wave owns 32 tokens (2 m-frags); weights read via fragment-major packed
// layout (fully coalesced); zero barriers; one occupancy round grid-wide.
__global__ __launch_bounds__(256, 5) void moe_kernel(
    const float* __restrict__ obs, const int* __restrict__ hete_type,
    const int* __restrict__ gp_sel,
    const float* __restrict__ b1, const float* __restrict__ b2,
    const float* __restrict__ bc1, const float* __restrict__ bc2,
    const int* __restrict__ counts, const int* __restrict__ order,
    const ushort* __restrict__ W1p, const ushort* __restrict__ W2p,
    const ushort* __restrict__ Wc1p, const float* __restrict__ Wc2,
    float* __restrict__ out)
{
    __shared__ __align__(16) ushort hbuf[4][32 * HB_STRIDE];   // per-wave h tile

    const int bx = blockIdx.x;
    const int e = bx % E_EXP;
    const int c = bx / E_EXP;
    const int cnt = counts[e * 16];
    const int tid = threadIdx.x;
    const int w = tid >> 6;
    const int base = c * BTOK + w * 32;        // this wave's token offset in bucket
    if (base >= cnt) return;                    // per-wave exit (no barriers anywhere)

    const int l = tid & 63;
    const int lm = l & 15;                      // A-row / n-col lane
    const int lq = l >> 4;                      // k-quad

    const int* ord_e = order + e * CAP;

    // ---- build A-fragments for 2 m-tiles directly from obs (+augment) ----
    bh8 a[2][4];
#pragma unroll
    for (int mt = 0; mt < 2; ++mt) {
        const int slot = min(base + mt * 16 + lm, cnt - 1);
        const int tok = ord_e[slot];
        const float* orow = obs + tok * RAWOB;
#pragma unroll
        for (int kt = 0; kt < 3; ++kt) {
            const float* p = orow + kt * 32 + lq * 8;
            float4 u0 = *(const float4*)(const void*)p;
            float4 u1 = *(const float4*)(const void*)(p + 4);
            u16x8 t;
            t[0] = f2bf(u0.x); t[1] = f2bf(u0.y); t[2] = f2bf(u0.z); t[3] = f2bf(u0.w);
            t[4] = f2bf(u1.x); t[5] = f2bf(u1.y); t[6] = f2bf(u1.z); t[7] = f2bf(u1.w);
            a[mt][kt] = __builtin_bit_cast(bh8, t);
        }
        u16x8 t;
        if (lq < 3) {   // k = 96..119 from obs
            const float* p = orow + 96 + lq * 8;
            float4 u0 = *(const float4*)(const void*)p;
            float4 u1 = *(const float4*)(const void*)(p + 4);
            t[0] = f2bf(u0.x); t[1] = f2bf(u0.y); t[2] = f2bf(u0.z); t[3] = f2bf(u0.w);
            t[4] = f2bf(u1.x); t[5] = f2bf(u1.y); t[6] = f2bf(u1.z); t[7] = f2bf(u1.w);
        } else {        // k = 120..127: [hete_type, gp_obs(5), 0, 0]
            int ht = hete_type[tok];
            int tt = tok >> 6;                  // token / A_DIM
            t[0] = f2bf((float)ht);
#pragma unroll
            for (int q = 0; q < N_TP; ++q) {
                float g = (q == ht) ? -1.0f : (float)gp_sel[tt * N_TP + q];
                t[1 + q] = f2bf(g);
            }
            t[6] = 0; t[7] = 0;
        }
        a[mt][3] = __builtin_bit_cast(bh8, t);
    }

    // ---- fused expert-L1 + critic-L1 over 8 n-tiles (coalesced packed B) ----
    ushort* hrow = &hbuf[w][0];
    const ushort* W1e = W1p + e * (H_DIM * DP);
    float part[2][4] = {{0.f,0.f,0.f,0.f},{0.f,0.f,0.f,0.f}};
#pragma unroll
    for (int nt = 0; nt < 8; ++nt) {
        const int n = nt * 16 + lm;
        f32x4 ae0 = (f32x4){0.f,0.f,0.f,0.f}, ae1 = ae0, ac0 = ae0, ac1 = ae0;
#pragma unroll
        for (int kt = 0; kt < 4; ++kt) {
            bh8 be = *(const bh8*)(const void*)(W1e + (nt * 4 + kt) * 512 + l * 8);
            bh8 bc = *(const bh8*)(const void*)(Wc1p + (nt * 4 + kt) * 512 + l * 8);
            ae0 = mfma16(a[0][kt], be, ae0);
            ae1 = mfma16(a[1][kt], be, ae1);
            ac0 = mfma16(a[0][kt], bc, ac0);
            ac1 = mfma16(a[1][kt], bc, ac1);
        }
        float bn = b1[e * H_DIM + n];
        float cn = bc1[n];
        float wc = Wc2[n];
#pragma unroll
        for (int r = 0; r < 4; ++r) {
            // C layout: col = lm (= n), row within 16 = lq*4 + r
            hrow[(lq * 4 + r) * HB_STRIDE + n] = f2bf(fmaxf(ae0[r] + bn, 0.f));
            hrow[(16 + lq * 4 + r) * HB_STRIDE + n] = f2bf(fmaxf(ae1[r] + bn, 0.f));
            part[0][r] += fmaxf(ac0[r] + cn, 0.f) * wc;
            part[1][r] += fmaxf(ac1[r] + cn, 0.f) * wc;
        }
    }

    // ---- critic: reduce partials over the 16 lm lanes, write values ----
#pragma unroll
    for (int mask = 1; mask < 16; mask <<= 1)
#pragma unroll
        for (int mt = 0; mt < 2; ++mt)
#pragma unroll
            for (int r = 0; r < 4; ++r)
                part[mt][r] += __shfl_xor(part[mt][r], mask, 64);
    if (lm == 0) {
        float bcv = bc2[0];
#pragma unroll
        for (int mt = 0; mt < 2; ++mt)
#pragma unroll
            for (int r = 0; r < 4; ++r) {
                int m = mt * 16 + lq * 4 + r;
                if (base + m < cnt)
                    out[LOGITS_SZ + ord_e[base + m]] = part[mt][r] + bcv;
            }
    }

    // ---- expert layer 2: y = h @ W2[e] + b2[e] (packed B, h from LDS) ----
    {
        f32x4 y0 = (f32x4){0.f,0.f,0.f,0.f}, y1 = y0;
#pragma unroll
        for (int kt = 0; kt < 4; ++kt) {
            bh8 bf = *(const bh8*)(const void*)(W2p + (e * 4 + kt) * 512 + l * 8);
            bh8 h0 = *(const bh8*)(const void*)(hrow + lm * HB_STRIDE + kt * 32 + lq * 8);
            bh8 h1 = *(const bh8*)(const void*)(hrow + (16 + lm) * HB_STRIDE + kt * 32 + lq * 8);
            y0 = mfma16(h0, bf, y0);
            y1 = mfma16(h1, bf, y1);
        }
        float bb = b2[e * N_ACT + lm];
#pragma unroll
        for (int r = 0; r < 4; ++r) {
            int m0 = lq * 4 + r;
            if (base + m0 < cnt)
                out[ord_e[base + m0] * N_ACT + lm] = y0[r] + bb;
            int m1 = 16 + lq * 4 + r;
            if (base + m1 < cnt)
                out[ord_e[base + m1] * N_ACT + lm] = y1[r] + bb;
        }
    }
}

extern "C" void kernel_launch(void* const* d_in, const int* in_sizes, int n_in,
                              void* d_out, int out_size, void* d_ws, size_t ws_size,
                              hipStream_t stream) {
    const float* obs  = (const float*)d_in[0];
    const int*   pick = (const int*)d_in[1];
    const int*   htyp = (const int*)d_in[2];
    const int*   gp   = (const int*)d_in[3];
    const float* W1   = (const float*)d_in[4];
    const float* b1   = (const float*)d_in[5];
    const float* W2   = (const float*)d_in[6];
    const float* b2   = (const float*)d_in[7];
    const float* Wc1  = (const float*)d_in[8];
    const float* bc1  = (const float*)d_in[9];
    const float* Wc2  = (const float*)d_in[10];
    const float* bc2  = (const float*)d_in[11];
    float* out = (float*)d_out;

    int*    counts = (int*)d_ws;              // 160 ints (padded, e -> counts[e*16])
    int*    order  = counts + 160;            // E_EXP * CAP ints
    ushort* W1p    = (ushort*)(order + E_EXP * CAP);
    ushort* W2p    = W1p + W1P_N;
    ushort* Wc1p   = W2p + W2P_N;

    prep_kernel<<<PREP_BLOCKS, 256, 0, stream>>>(
        W1, W2, Wc1, counts, W1p, W2p, Wc1p);
    bucket_kernel<<<BUCKET_BLOCKS, 256, 0, stream>>>(pick, counts, order);
    moe_kernel<<<E_EXP * MAXC, 256, 0, stream>>>(
        obs, htyp, gp, b1, b2, bc1, bc2, counts, order,
        W1p, W2p, Wc1p, Wc2, out);
}

// Round 9
// 148.063 us; speedup vs baseline: 1.2968x; 1.0176x over previous
//
#include <hip/hip_runtime.h>
#include <hip/hip_bf16.h>

// ---- problem constants ----
#define T_DIM   2048
#define A_DIM   64
#define N_TOK   (T_DIM * A_DIM)     // 131072
#define RAWOB   120
#define N_TP    5
#define E_EXP   10
#define D_DIM   126                  // RAWOB + N_TP + 1
#define DP      128                  // padded K
#define H_DIM   128
#define N_ACT   16
#define CAP     14336                // per-expert capacity (mean 13107, +11 sigma)
#define BTOK    128                  // tokens per block (4 waves x 32)
#define MAXC    (CAP / BTOK)         // 112 chunks per expert
#define LOGITS_SZ (N_TOK * N_ACT)    // 2097152
#define HB_STRIDE 136                // padded h-tile row stride (ushorts, 16B-aligned)

typedef __bf16 bh8 __attribute__((ext_vector_type(8)));
typedef ushort u16x8 __attribute__((ext_vector_type(8)));
typedef float  f32x4 __attribute__((ext_vector_type(4)));

__device__ __forceinline__ f32x4 mfma16(bh8 a, bh8 b, f32x4 c) {
    return __builtin_amdgcn_mfma_f32_16x16x32_bf16(a, b, c, 0, 0, 0);
}

__device__ __forceinline__ ushort f2bf(float f) {
    unsigned x = __builtin_bit_cast(unsigned, f);
    unsigned r = (x + 0x7fffu + ((x >> 16) & 1u)) >> 16;   // round-nearest-even
    return (ushort)r;
}

// ---------------- kernel 0: fragment-major weight packing (f32 -> bf16) ----------
// W1p[e][nt][kt][lane][8]: the 1KB B-fragment a wave consumes per (nt,kt) is
// contiguous; lane l (lm=l&15, lq=l>>4) holds W1[d=kt*32+lq*8 .. +8][n=nt*16+lm].
// Same for Wc1p (no e) and W2p[e][kt][lane][8] (n -> action).
#define W1P_N (E_EXP * H_DIM * DP)           // 163840 ushorts
#define W2P_N (E_EXP * N_ACT * H_DIM)        // 20480
#define WC1P_N (DP * DP)                     // 16384
#define PREP_BLOCKS 124

__global__ __launch_bounds__(256) void prep_kernel(
    const float* __restrict__ W1, const float* __restrict__ W2,
    const float* __restrict__ Wc1,
    int* __restrict__ counts, ushort* __restrict__ W1p,
    ushort* __restrict__ W2p, ushort* __restrict__ Wc1p)
{
    int bx = blockIdx.x, tid = threadIdx.x;
    if (bx < 44) {
        __shared__ ushort st[32][130];   // 32 d-rows x 128 n, padded
        const float* src;
        ushort* dstbase;
        int kt;
        if (bx < 40) {                   // W1: e = bx>>2, kt = bx&3
            int e = bx >> 2;
            kt = bx & 3;
            src = W1 + (e * D_DIM + kt * 32) * H_DIM;
            dstbase = W1p + e * (H_DIM * DP);
        } else {                         // Wc1: kt = bx-40
            kt = bx - 40;
            src = Wc1 + kt * 32 * H_DIM;
            dstbase = Wc1p;
        }
        int dmax = D_DIM - kt * 32;      // 32,32,32,30
#pragma unroll
        for (int p = 0; p < 16; ++p) {
            int idx = p * 256 + tid;
            int dd = idx >> 7, n = idx & 127;
            float v = (dd < dmax) ? src[dd * H_DIM + n] : 0.f;  // coalesced in n
            st[dd][n] = f2bf(v);
        }
        __syncthreads();
#pragma unroll
        for (int p = 0; p < 16; ++p) {
            int idx = p * 256 + tid;
            int dd = idx >> 7, n = idx & 127;
            // frag position: nt=n>>4, lm=n&15, lq=dd>>3, j=dd&7
            dstbase[((n >> 4) * 4 + kt) * 512 + ((dd >> 3) * 16 + (n & 15)) * 8 + (dd & 7)]
                = st[dd][n];
        }
    } else {
        int i = (bx - 44) * 256 + tid;   // [0, 20480)
        int j = i & 7;
        int l = (i >> 3) & 63;
        int kt = (i >> 9) & 3;
        int e = i >> 11;
        int lm = l & 15, lq = l >> 4;
        W2p[i] = f2bf(W2[(e * H_DIM + kt * 32 + lq * 8 + j) * N_ACT + lm]);
        if (bx == 44 && tid < 160) counts[tid] = 0;
    }
}

// ---------------- kernel 1: bucket tokens by expert ----------------
// counts padded: expert e lives at counts[e*16] (own 64B line)
#define BUCKET_BLOCKS 128
__global__ __launch_bounds__(256) void bucket_kernel(
    const int* __restrict__ pick, int* __restrict__ counts, int* __restrict__ order)
{
    __shared__ int lc[E_EXP], lb[E_EXP], lcur[E_EXP];
    int tid = threadIdx.x;
    if (tid < E_EXP) { lc[tid] = 0; lcur[tid] = 0; }
    __syncthreads();
    int base = blockIdx.x * 1024;
    int e4[4];
#pragma unroll
    for (int it = 0; it < 4; ++it) {
        e4[it] = pick[base + it * 256 + tid];
        atomicAdd(&lc[e4[it]], 1);
    }
    __syncthreads();
    if (tid < E_EXP) lb[tid] = atomicAdd(&counts[tid * 16], lc[tid]);
    __syncthreads();
#pragma unroll
    for (int it = 0; it < 4; ++it) {
        int e = e4[it];
        int pos = lb[e] + atomicAdd(&lcur[e], 1);
        if (pos < CAP) order[e * CAP + pos] = base + it * 256 + tid;
    }
}

// ---------------- kernel 2: LDS-staged-weights fused expert + critic ------------
// Block = 4 waves x 32 tokens. Weights staged once per block into LDS; inner-loop
// B-fragments come from ds_read_b128 (128 B/cyc path) instead of per-wave global
// streams (the R7/R8 ~9-16 B/cyc/CU wall).
__global__ __launch_bounds__(256, 2) void moe_kernel(
    const float* __restrict__ obs, const int* __restrict__ hete_type,
    const int* __restrict__ gp_sel,
    const float* __restrict__ b1, const float* __restrict__ b2,
    const float* __restrict__ bc1, const float* __restrict__ bc2,
    const int* __restrict__ counts, const int* __restrict__ order,
    const ushort* __restrict__ W1p, const ushort* __restrict__ W2p,
    const ushort* __restrict__ Wc1p, const float* __restrict__ Wc2,
    float* __restrict__ out)
{
    __shared__ __align__(16) ushort wlds[18432];               // 32KB W1e/Wc1 + 4KB W2e
    __shared__ __align__(16) ushort hbuf[4][32 * HB_STRIDE];   // per-wave h tile

    const int bx = blockIdx.x;
    const int e = bx % E_EXP;
    const int c = bx / E_EXP;
    const int cnt = counts[e * 16];
    const int start = c * BTOK;
    if (start >= cnt) return;                   // uniform block exit (before barriers)

    const int tid = threadIdx.x;
    const int w = tid >> 6;
    const int base = start + w * 32;            // this wave's token offset
    const int l = tid & 63;
    const int lm = l & 15;
    const int lq = l >> 4;

    // ---- stage W1e (32KB) + W2e (4KB) packed frags into LDS ----
    {
        const u16x8* s1 = (const u16x8*)(const void*)(W1p + e * (H_DIM * DP));
        u16x8* d1 = (u16x8*)(void*)wlds;
#pragma unroll
        for (int p = 0; p < 8; ++p) d1[p * 256 + tid] = s1[p * 256 + tid];
        ((u16x8*)(void*)(wlds + 16384))[tid] =
            ((const u16x8*)(const void*)(W2p + e * 2048))[tid];
    }

    const int* ord_e = order + e * CAP;

    // ---- build A-fragments for 2 m-tiles directly from obs (+augment) ----
    bh8 a[2][4];
#pragma unroll
    for (int mt = 0; mt < 2; ++mt) {
        const int slot = min(base + mt * 16 + lm, cnt - 1);
        const int tok = ord_e[slot];
        const float* orow = obs + tok * RAWOB;
#pragma unroll
        for (int kt = 0; kt < 3; ++kt) {
            const float* p = orow + kt * 32 + lq * 8;
            float4 u0 = *(const float4*)(const void*)p;
            float4 u1 = *(const float4*)(const void*)(p + 4);
            u16x8 t;
            t[0] = f2bf(u0.x); t[1] = f2bf(u0.y); t[2] = f2bf(u0.z); t[3] = f2bf(u0.w);
            t[4] = f2bf(u1.x); t[5] = f2bf(u1.y); t[6] = f2bf(u1.z); t[7] = f2bf(u1.w);
            a[mt][kt] = __builtin_bit_cast(bh8, t);
        }
        u16x8 t;
        if (lq < 3) {   // k = 96..119 from obs
            const float* p = orow + 96 + lq * 8;
            float4 u0 = *(const float4*)(const void*)p;
            float4 u1 = *(const float4*)(const void*)(p + 4);
            t[0] = f2bf(u0.x); t[1] = f2bf(u0.y); t[2] = f2bf(u0.z); t[3] = f2bf(u0.w);
            t[4] = f2bf(u1.x); t[5] = f2bf(u1.y); t[6] = f2bf(u1.z); t[7] = f2bf(u1.w);
        } else {        // k = 120..127: [hete_type, gp_obs(5), 0, 0]
            int ht = hete_type[tok];
            int tt = tok >> 6;                  // token / A_DIM
            t[0] = f2bf((float)ht);
#pragma unroll
            for (int q = 0; q < N_TP; ++q) {
                float g = (q == ht) ? -1.0f : (float)gp_sel[tt * N_TP + q];
                t[1 + q] = f2bf(g);
            }
            t[6] = 0; t[7] = 0;
        }
        a[mt][3] = __builtin_bit_cast(bh8, t);
    }

    // ---- preload per-n scalars (overlap with staging) ----
    float bnv[8], cnv[8], wcv[8];
#pragma unroll
    for (int nt = 0; nt < 8; ++nt) {
        int n = nt * 16 + lm;
        bnv[nt] = b1[e * H_DIM + n];
        cnv[nt] = bc1[n];
        wcv[nt] = Wc2[n];
    }
    const float bb  = b2[e * N_ACT + lm];
    const float bcv = bc2[0];

    __syncthreads();   // W1e/W2e staged

    // ---- expert layer 1: B-frags from LDS ----
    ushort* hrow = &hbuf[w][0];
#pragma unroll
    for (int nt = 0; nt < 8; ++nt) {
        const int n = nt * 16 + lm;
        f32x4 ae0 = (f32x4){0.f,0.f,0.f,0.f}, ae1 = ae0;
#pragma unroll
        for (int kt = 0; kt < 4; ++kt) {
            bh8 be = *(const bh8*)(const void*)(wlds + (nt * 4 + kt) * 512 + l * 8);
            ae0 = mfma16(a[0][kt], be, ae0);
            ae1 = mfma16(a[1][kt], be, ae1);
        }
        float bn = bnv[nt];
#pragma unroll
        for (int r = 0; r < 4; ++r) {
            hrow[(lq * 4 + r) * HB_STRIDE + n] = f2bf(fmaxf(ae0[r] + bn, 0.f));
            hrow[(16 + lq * 4 + r) * HB_STRIDE + n] = f2bf(fmaxf(ae1[r] + bn, 0.f));
        }
    }

    // ---- expert layer 2: y = h @ W2[e] + b2[e] (B from LDS, h from own tile) ----
    {
        f32x4 y0 = (f32x4){0.f,0.f,0.f,0.f}, y1 = y0;
#pragma unroll
        for (int kt = 0; kt < 4; ++kt) {
            bh8 bf = *(const bh8*)(const void*)(wlds + 16384 + kt * 512 + l * 8);
            bh8 h0 = *(const bh8*)(const void*)(hrow + lm * HB_STRIDE + kt * 32 + lq * 8);
            bh8 h1 = *(const bh8*)(const void*)(hrow + (16 + lm) * HB_STRIDE + kt * 32 + lq * 8);
            y0 = mfma16(h0, bf, y0);
            y1 = mfma16(h1, bf, y1);
        }
#pragma unroll
        for (int r = 0; r < 4; ++r) {
            int m0 = lq * 4 + r;
            if (base + m0 < cnt)
                out[ord_e[base + m0] * N_ACT + lm] = y0[r] + bb;
            int m1 = 16 + lq * 4 + r;
            if (base + m1 < cnt)
                out[ord_e[base + m1] * N_ACT + lm] = y1[r] + bb;
        }
    }

    __syncthreads();   // everyone done with W1e buffer

    // ---- stage Wc1p into the same buffer ----
    {
        const u16x8* s1 = (const u16x8*)(const void*)Wc1p;
        u16x8* d1 = (u16x8*)(void*)wlds;
#pragma unroll
        for (int p = 0; p < 8; ++p) d1[p * 256 + tid] = s1[p * 256 + tid];
    }
    __syncthreads();

    // ---- critic layer 1 + dot(Wc2) in registers (B from LDS) ----
    {
        float part[2][4] = {{0.f,0.f,0.f,0.f},{0.f,0.f,0.f,0.f}};
#pragma unroll
        for (int nt = 0; nt < 8; ++nt) {
            f32x4 ac0 = (f32x4){0.f,0.f,0.f,0.f}, ac1 = ac0;
#pragma unroll
            for (int kt = 0; kt < 4; ++kt) {
                bh8 bc = *(const bh8*)(const void*)(wlds + (nt * 4 + kt) * 512 + l * 8);
                ac0 = mfma16(a[0][kt], bc, ac0);
                ac1 = mfma16(a[1][kt], bc, ac1);
            }
            float cn = cnv[nt], wc = wcv[nt];
#pragma unroll
            for (int r = 0; r < 4; ++r) {
                part[0][r] += fmaxf(ac0[r] + cn, 0.f) * wc;
                part[1][r] += fmaxf(ac1[r] + cn, 0.f) * wc;
            }
        }
#pragma unroll
        for (int mask = 1; mask < 16; mask <<= 1)
#pragma unroll
            for (int mt = 0; mt < 2; ++mt)
#pragma unroll
                for (int r = 0; r < 4; ++r)
                    part[mt][r] += __shfl_xor(part[mt][r], mask, 64);
        if (lm == 0) {
#pragma unroll
            for (int mt = 0; mt < 2; ++mt)
#pragma unroll
                for (int r = 0; r < 4; ++r) {
                    int m = mt * 16 + lq * 4 + r;
                    if (base + m < cnt)
                        out[LOGITS_SZ + ord_e[base + m]] = part[mt][r] + bcv;
                }
        }
    }
}

extern "C" void kernel_launch(void* const* d_in, const int* in_sizes, int n_in,
                              void* d_out, int out_size, void* d_ws, size_t ws_size,
                              hipStream_t stream) {
    const float* obs  = (const float*)d_in[0];
    const int*   pick = (const int*)d_in[1];
    const int*   htyp = (const int*)d_in[2];
    const int*   gp   = (const int*)d_in[3];
    const float* W1   = (const float*)d_in[4];
    const float* b1   = (const float*)d_in[5];
    const float* W2   = (const float*)d_in[6];
    const float* b2   = (const float*)d_in[7];
    const float* Wc1  = (const float*)d_in[8];
    const float* bc1  = (const float*)d_in[9];
    const float* Wc2  = (const float*)d_in[10];
    const float* bc2  = (const float*)d_in[11];
    float* out = (float*)d_out;

    int*    counts = (int*)d_ws;              // 160 ints (padded, e -> counts[e*16])
    int*    order  = counts + 160;            // E_EXP * CAP ints
    ushort* W1p    = (ushort*)(order + E_EXP * CAP);
    ushort* W2p    = W1p + W1P_N;
    ushort* Wc1p   = W2p + W2P_N;

    prep_kernel<<<PREP_BLOCKS, 256, 0, stream>>>(
        W1, W2, Wc1, counts, W1p, W2p, Wc1p);
    bucket_kernel<<<BUCKET_BLOCKS, 256, 0, stream>>>(pick, counts, order);
    moe_kernel<<<E_EXP * MAXC, 256, 0, stream>>>(
        obs, htyp, gp, b1, b2, bc1, bc2, counts, order,
        W1p, W2p, Wc1p, Wc2, out);
}

// Round 10
// 140.272 us; speedup vs baseline: 1.3688x; 1.0555x over previous
//
#include <hip/hip_runtime.h>
#include <hip/hip_bf16.h>

// ---- problem constants ----
#define T_DIM   2048
#define A_DIM   64
#define N_TOK   (T_DIM * A_DIM)     // 131072
#define RAWOB   120
#define N_TP    5
#define E_EXP   10
#define D_DIM   126                  // RAWOB + N_TP + 1
#define DP      128                  // padded K
#define H_DIM   128
#define N_ACT   16
#define CAP     14336                // per-expert capacity (mean 13107, +11 sigma)
#define BTOK    256                  // tokens per block (8 waves x 32)
#define MAXC    (CAP / BTOK)         // 56 chunks per expert
#define LOGITS_SZ (N_TOK * N_ACT)    // 2097152
#define HB_STRIDE 136                // padded h-tile row stride (ushorts, 16B-aligned)

typedef __bf16 bh8 __attribute__((ext_vector_type(8)));
typedef ushort u16x8 __attribute__((ext_vector_type(8)));
typedef float  f32x4 __attribute__((ext_vector_type(4)));

__device__ __forceinline__ f32x4 mfma16(bh8 a, bh8 b, f32x4 c) {
    return __builtin_amdgcn_mfma_f32_16x16x32_bf16(a, b, c, 0, 0, 0);
}

__device__ __forceinline__ ushort f2bf(float f) {
    unsigned x = __builtin_bit_cast(unsigned, f);
    unsigned r = (x + 0x7fffu + ((x >> 16) & 1u)) >> 16;   // round-nearest-even
    return (ushort)r;
}

#define W1P_N (E_EXP * H_DIM * DP)           // 163840 ushorts
#define W2P_N (E_EXP * N_ACT * H_DIM)        // 20480
#define WC1P_N (DP * DP)                     // 16384

// ---------------- kernel 0: merged prep (fragment packing) + bucket ----------------
// blocks 0..123: weight packing (f32 -> bf16, fragment-major; see R8 comments)
// blocks 124..251: token bucketing (counts pre-zeroed via hipMemsetAsync)
#define PB_BLOCKS 252

__global__ __launch_bounds__(256) void prep_bucket_kernel(
    const float* __restrict__ W1, const float* __restrict__ W2,
    const float* __restrict__ Wc1, const int* __restrict__ pick,
    int* __restrict__ counts, int* __restrict__ order,
    ushort* __restrict__ W1p, ushort* __restrict__ W2p, ushort* __restrict__ Wc1p)
{
    int bx = blockIdx.x, tid = threadIdx.x;
    if (bx < 44) {
        __shared__ ushort st[32][130];   // 32 d-rows x 128 n, padded
        const float* src;
        ushort* dstbase;
        int kt;
        if (bx < 40) {                   // W1: e = bx>>2, kt = bx&3
            int e = bx >> 2;
            kt = bx & 3;
            src = W1 + (e * D_DIM + kt * 32) * H_DIM;
            dstbase = W1p + e * (H_DIM * DP);
        } else {                         // Wc1: kt = bx-40
            kt = bx - 40;
            src = Wc1 + kt * 32 * H_DIM;
            dstbase = Wc1p;
        }
        int dmax = D_DIM - kt * 32;      // 32,32,32,30
#pragma unroll
        for (int p = 0; p < 16; ++p) {
            int idx = p * 256 + tid;
            int dd = idx >> 7, n = idx & 127;
            float v = (dd < dmax) ? src[dd * H_DIM + n] : 0.f;  // coalesced in n
            st[dd][n] = f2bf(v);
        }
        __syncthreads();
#pragma unroll
        for (int p = 0; p < 16; ++p) {
            int idx = p * 256 + tid;
            int dd = idx >> 7, n = idx & 127;
            // frag position: nt=n>>4, lm=n&15, lq=dd>>3, j=dd&7
            dstbase[((n >> 4) * 4 + kt) * 512 + ((dd >> 3) * 16 + (n & 15)) * 8 + (dd & 7)]
                = st[dd][n];
        }
    } else if (bx < 124) {
        int i = (bx - 44) * 256 + tid;   // [0, 20480)
        int j = i & 7;
        int l = (i >> 3) & 63;
        int kt = (i >> 9) & 3;
        int e = i >> 11;
        int lm = l & 15, lq = l >> 4;
        W2p[i] = f2bf(W2[(e * H_DIM + kt * 32 + lq * 8 + j) * N_ACT + lm]);
    } else {
        // ---- bucket: counts padded, expert e at counts[e*16] ----
        __shared__ int lc[E_EXP], lb[E_EXP], lcur[E_EXP];
        if (tid < E_EXP) { lc[tid] = 0; lcur[tid] = 0; }
        __syncthreads();
        int base = (bx - 124) * 1024;
        int e4[4];
#pragma unroll
        for (int it = 0; it < 4; ++it) {
            e4[it] = pick[base + it * 256 + tid];
            atomicAdd(&lc[e4[it]], 1);
        }
        __syncthreads();
        if (tid < E_EXP) lb[tid] = atomicAdd(&counts[tid * 16], lc[tid]);
        __syncthreads();
#pragma unroll
        for (int it = 0; it < 4; ++it) {
            int e = e4[it];
            int pos = lb[e] + atomicAdd(&lcur[e], 1);
            if (pos < CAP) order[e * CAP + pos] = base + it * 256 + tid;
        }
    }
}

// ---------------- kernel 1: LDS-staged-weights fused expert + critic ------------
// 512 threads = 8 waves x 32 tokens. One 36KB weight stage shared by 8 waves;
// per-wave 16-row h tile (reused across the 2 m-frags). 2 blocks/CU -> 16 waves/CU.
__global__ __launch_bounds__(512, 4) void moe_kernel(
    const float* __restrict__ obs, const int* __restrict__ hete_type,
    const int* __restrict__ gp_sel,
    const float* __restrict__ b1, const float* __restrict__ b2,
    const float* __restrict__ bc1, const float* __restrict__ bc2,
    const int* __restrict__ counts, const int* __restrict__ order,
    const ushort* __restrict__ W1p, const ushort* __restrict__ W2p,
    const ushort* __restrict__ Wc1p, const float* __restrict__ Wc2,
    float* __restrict__ out)
{
    __shared__ __align__(16) ushort wlds[18432];               // 32KB W1e/Wc1 + 4KB W2e
    __shared__ __align__(16) ushort hbuf[8][16 * HB_STRIDE];   // per-wave h tile (per-mt)

    const int bx = blockIdx.x;
    const int e = bx % E_EXP;
    const int c = bx / E_EXP;
    const int cnt = counts[e * 16];
    const int start = c * BTOK;
    if (start >= cnt) return;                   // uniform block exit (before barriers)

    const int tid = threadIdx.x;
    const int w = tid >> 6;
    const int base = start + w * 32;            // this wave's token offset (may exceed cnt)
    const int l = tid & 63;
    const int lm = l & 15;
    const int lq = l >> 4;

    // ---- stage W1e (32KB) + W2e (4KB) packed frags into LDS (512 threads) ----
    {
        const u16x8* s1 = (const u16x8*)(const void*)(W1p + e * (H_DIM * DP));
        u16x8* d1 = (u16x8*)(void*)wlds;
#pragma unroll
        for (int p = 0; p < 4; ++p) d1[p * 512 + tid] = s1[p * 512 + tid];
        if (tid < 256)
            ((u16x8*)(void*)(wlds + 16384))[tid] =
                ((const u16x8*)(const void*)(W2p + e * 2048))[tid];
    }

    const int* ord_e = order + e * CAP;

    // ---- build A-fragments for 2 m-tiles directly from obs (+augment) ----
    bh8 a[2][4];
#pragma unroll
    for (int mt = 0; mt < 2; ++mt) {
        const int slot = min(base + mt * 16 + lm, cnt - 1);
        const int tok = ord_e[slot];
        const float* orow = obs + tok * RAWOB;
#pragma unroll
        for (int kt = 0; kt < 3; ++kt) {
            const float* p = orow + kt * 32 + lq * 8;
            float4 u0 = *(const float4*)(const void*)p;
            float4 u1 = *(const float4*)(const void*)(p + 4);
            u16x8 t;
            t[0] = f2bf(u0.x); t[1] = f2bf(u0.y); t[2] = f2bf(u0.z); t[3] = f2bf(u0.w);
            t[4] = f2bf(u1.x); t[5] = f2bf(u1.y); t[6] = f2bf(u1.z); t[7] = f2bf(u1.w);
            a[mt][kt] = __builtin_bit_cast(bh8, t);
        }
        u16x8 t;
        if (lq < 3) {   // k = 96..119 from obs
            const float* p = orow + 96 + lq * 8;
            float4 u0 = *(const float4*)(const void*)p;
            float4 u1 = *(const float4*)(const void*)(p + 4);
            t[0] = f2bf(u0.x); t[1] = f2bf(u0.y); t[2] = f2bf(u0.z); t[3] = f2bf(u0.w);
            t[4] = f2bf(u1.x); t[5] = f2bf(u1.y); t[6] = f2bf(u1.z); t[7] = f2bf(u1.w);
        } else {        // k = 120..127: [hete_type, gp_obs(5), 0, 0]
            int ht = hete_type[tok];
            int tt = tok >> 6;                  // token / A_DIM
            t[0] = f2bf((float)ht);
#pragma unroll
            for (int q = 0; q < N_TP; ++q) {
                float g = (q == ht) ? -1.0f : (float)gp_sel[tt * N_TP + q];
                t[1 + q] = f2bf(g);
            }
            t[6] = 0; t[7] = 0;
        }
        a[mt][3] = __builtin_bit_cast(bh8, t);
    }

    // ---- preload per-n scalars ----
    float bnv[8];
#pragma unroll
    for (int nt = 0; nt < 8; ++nt) bnv[nt] = b1[e * H_DIM + nt * 16 + lm];
    const float bb  = b2[e * N_ACT + lm];
    const float bcv = bc2[0];

    __syncthreads();   // W1e/W2e staged

    // ---- expert path per m-frag: L1 -> h tile -> L2 -> scatter (wave-local) ----
    ushort* hrow = &hbuf[w][0];
#pragma unroll
    for (int mt = 0; mt < 2; ++mt) {
#pragma unroll
        for (int nt = 0; nt < 8; ++nt) {
            const int n = nt * 16 + lm;
            f32x4 ae = (f32x4){0.f, 0.f, 0.f, 0.f};
#pragma unroll
            for (int kt = 0; kt < 4; ++kt) {
                bh8 be = *(const bh8*)(const void*)(wlds + (nt * 4 + kt) * 512 + l * 8);
                ae = mfma16(a[mt][kt], be, ae);
            }
            float bn = bnv[nt];
#pragma unroll
            for (int r = 0; r < 4; ++r)
                hrow[(lq * 4 + r) * HB_STRIDE + n] = f2bf(fmaxf(ae[r] + bn, 0.f));
        }
        f32x4 y = (f32x4){0.f, 0.f, 0.f, 0.f};
#pragma unroll
        for (int kt = 0; kt < 4; ++kt) {
            bh8 bf = *(const bh8*)(const void*)(wlds + 16384 + kt * 512 + l * 8);
            bh8 hf = *(const bh8*)(const void*)(hrow + lm * HB_STRIDE + kt * 32 + lq * 8);
            y = mfma16(hf, bf, y);
        }
#pragma unroll
        for (int r = 0; r < 4; ++r) {
            int m = mt * 16 + lq * 4 + r;
            if (base + m < cnt)
                out[ord_e[base + m] * N_ACT + lm] = y[r] + bb;
        }
    }

    __syncthreads();   // everyone done with W1e buffer

    // ---- re-stage Wc1p into the same buffer ----
    {
        const u16x8* s1 = (const u16x8*)(const void*)Wc1p;
        u16x8* d1 = (u16x8*)(void*)wlds;
#pragma unroll
        for (int p = 0; p < 4; ++p) d1[p * 512 + tid] = s1[p * 512 + tid];
    }
    __syncthreads();

    // ---- critic layer 1 + dot(Wc2) in registers (B from LDS) ----
    {
        float part[2][4] = {{0.f,0.f,0.f,0.f},{0.f,0.f,0.f,0.f}};
#pragma unroll
        for (int nt = 0; nt < 8; ++nt) {
            const int n = nt * 16 + lm;
            f32x4 ac0 = (f32x4){0.f,0.f,0.f,0.f}, ac1 = ac0;
#pragma unroll
            for (int kt = 0; kt < 4; ++kt) {
                bh8 bc = *(const bh8*)(const void*)(wlds + (nt * 4 + kt) * 512 + l * 8);
                ac0 = mfma16(a[0][kt], bc, ac0);
                ac1 = mfma16(a[1][kt], bc, ac1);
            }
            float cn = bc1[n], wc = Wc2[n];
#pragma unroll
            for (int r = 0; r < 4; ++r) {
                part[0][r] += fmaxf(ac0[r] + cn, 0.f) * wc;
                part[1][r] += fmaxf(ac1[r] + cn, 0.f) * wc;
            }
        }
#pragma unroll
        for (int mask = 1; mask < 16; mask <<= 1)
#pragma unroll
            for (int mt = 0; mt < 2; ++mt)
#pragma unroll
                for (int r = 0; r < 4; ++r)
                    part[mt][r] += __shfl_xor(part[mt][r], mask, 64);
        if (lm == 0) {
#pragma unroll
            for (int mt = 0; mt < 2; ++mt)
#pragma unroll
                for (int r = 0; r < 4; ++r) {
                    int m = mt * 16 + lq * 4 + r;
                    if (base + m < cnt)
                        out[LOGITS_SZ + ord_e[base + m]] = part[mt][r] + bcv;
                }
        }
    }
}

extern "C" void kernel_launch(void* const* d_in, const int* in_sizes, int n_in,
                              void* d_out, int out_size, void* d_ws, size_t ws_size,
                              hipStream_t stream) {
    const float* obs  = (const float*)d_in[0];
    const int*   pick = (const int*)d_in[1];
    const int*   htyp = (const int*)d_in[2];
    const int*   gp   = (const int*)d_in[3];
    const float* W1   = (const float*)d_in[4];
    const float* b1   = (const float*)d_in[5];
    const float* W2   = (const float*)d_in[6];
    const float* b2   = (const float*)d_in[7];
    const float* Wc1  = (const float*)d_in[8];
    const float* bc1  = (const float*)d_in[9];
    const float* Wc2  = (const float*)d_in[10];
    const float* bc2  = (const float*)d_in[11];
    float* out = (float*)d_out;

    int*    counts = (int*)d_ws;              // 160 ints (padded, e -> counts[e*16])
    int*    order  = counts + 160;            // E_EXP * CAP ints
    ushort* W1p    = (ushort*)(order + E_EXP * CAP);
    ushort* W2p    = W1p + W1P_N;
    ushort* Wc1p   = W2p + W2P_N;

    hipMemsetAsync(counts, 0, 160 * sizeof(int), stream);
    prep_bucket_kernel<<<PB_BLOCKS, 256, 0, stream>>>(
        W1, W2, Wc1, pick, counts, order, W1p, W2p, Wc1p);
    moe_kernel<<<E_EXP * MAXC, 512, 0, stream>>>(
        obs, htyp, gp, b1, b2, bc1, bc2, counts, order,
        W1p, W2p, Wc1p, Wc2, out);
}